// Round 2
// baseline (2045.422 us; speedup 1.0000x reference)
//
#include <hip/hip_runtime.h>
#include <stdint.h>

#define BATCH   16
#define NPTS    4096
#define NPOINT  1024
#define NSAMPLE 32
#define NPOS    (BATCH*NPOINT*NSAMPLE)   // 524288
#define EPSV    1e-5f

typedef unsigned short ushort_t;
typedef unsigned int uint_t;
typedef unsigned long long u64;

__device__ inline ushort_t f2bf(float f) {
    uint_t u = __float_as_uint(f);
    u += 0x7fffu + ((u >> 16) & 1u);   // RNE (no NaNs in this workload)
    return (ushort_t)(u >> 16);
}
__device__ inline void unpack8(uint4 u, float* f) {
    f[0] = __uint_as_float(u.x << 16); f[1] = __uint_as_float(u.x & 0xffff0000u);
    f[2] = __uint_as_float(u.y << 16); f[3] = __uint_as_float(u.y & 0xffff0000u);
    f[4] = __uint_as_float(u.z << 16); f[5] = __uint_as_float(u.z & 0xffff0000u);
    f[6] = __uint_as_float(u.w << 16); f[7] = __uint_as_float(u.w & 0xffff0000u);
}
__device__ inline uint4 pack8(const float* a) {
    uint4 r;
    r.x = (uint_t)f2bf(a[0]) | ((uint_t)f2bf(a[1]) << 16);
    r.y = (uint_t)f2bf(a[2]) | ((uint_t)f2bf(a[3]) << 16);
    r.z = (uint_t)f2bf(a[4]) | ((uint_t)f2bf(a[5]) << 16);
    r.w = (uint_t)f2bf(a[6]) | ((uint_t)f2bf(a[7]) << 16);
    return r;
}

// ---------------------------------------------------------------- zero stats
__global__ void zero_kernel(float* __restrict__ p, int n) {
    int i = blockIdx.x * blockDim.x + threadIdx.x;
    if (i < n) p[i] = 0.f;
}

// ---------------------------------------------------------------- FPS
// One block per batch. xyz in LDS (SoA), 48 KiB. 1024 threads x 4 pts each.
// Exact fp32 op order (no FMA contraction) to match np reference argmax.
__global__ __launch_bounds__(1024) void fps_kernel(const float* __restrict__ xyz,
                                                   float* __restrict__ new_xyz) {
    __shared__ float lx[NPTS], ly[NPTS], lz[NPTS];
    __shared__ u64 wbest[16];
    __shared__ int cur_s;
    const int b = blockIdx.x;
    const int tid = threadIdx.x;
    const float* base = xyz + (size_t)b * NPTS * 3;
    for (int n = tid; n < NPTS; n += 1024) {
        lx[n] = base[n * 3 + 0];
        ly[n] = base[n * 3 + 1];
        lz[n] = base[n * 3 + 2];
    }
    __syncthreads();

    float px[4], py[4], pz[4], dist[4];
#pragma unroll
    for (int j = 0; j < 4; j++) {
        int n = tid + j * 1024;
        px[j] = lx[n]; py[j] = ly[n]; pz[j] = lz[n];
        dist[j] = 1e10f;
    }
    if (tid == 0) {
        float* o = new_xyz + (size_t)b * NPOINT * 3;
        o[0] = lx[0]; o[1] = ly[0]; o[2] = lz[0];
    }
    int cur = 0;
    const int lane = tid & 63, wid = tid >> 6;

    for (int it = 1; it < NPOINT; ++it) {
        float cx = lx[cur], cy = ly[cur], cz = lz[cur];
        u64 best = 0;
#pragma unroll
        for (int j = 0; j < 4; j++) {
            float dx = __fsub_rn(px[j], cx);
            float dy = __fsub_rn(py[j], cy);
            float dz = __fsub_rn(pz[j], cz);
            float d = __fadd_rn(__fadd_rn(__fmul_rn(dx, dx), __fmul_rn(dy, dy)),
                                __fmul_rn(dz, dz));
            dist[j] = fminf(dist[j], d);
            // dist >= 0 so float bits are order-preserving as unsigned.
            // tie-break: smaller index wins  ->  pack ~idx in low bits.
            u64 pk = ((u64)__float_as_uint(dist[j]) << 32) |
                     (uint_t)(0xFFFFFFFFu - (uint_t)(tid + j * 1024));
            best = best > pk ? best : pk;
        }
#pragma unroll
        for (int m = 32; m >= 1; m >>= 1) {
            u64 o = __shfl_xor(best, m, 64);
            best = best > o ? best : o;
        }
        if (lane == 0) wbest[wid] = best;
        __syncthreads();
        if (tid == 0) {
            u64 bb = wbest[0];
#pragma unroll
            for (int w = 1; w < 16; w++) bb = bb > wbest[w] ? bb : wbest[w];
            int idx = (int)(0xFFFFFFFFu - (uint_t)(bb & 0xFFFFFFFFu));
            cur_s = idx;
            float* o = new_xyz + ((size_t)b * NPOINT + it) * 3;
            o[0] = lx[idx]; o[1] = ly[idx]; o[2] = lz[idx];
        }
        __syncthreads();
        cur = cur_s;
    }
}

// ---------------------------------------------------------------- ball query
// One wave per centroid; ordered compaction of first NSAMPLE in-radius idx.
__global__ __launch_bounds__(256) void ballq_kernel(const float* __restrict__ xyz,
                                                    const float* __restrict__ new_xyz,
                                                    int* __restrict__ gidx) {
    const int gw = (int)((blockIdx.x * 256 + threadIdx.x) >> 6);
    const int lane = threadIdx.x & 63;
    const int b = gw / NPOINT, s = gw % NPOINT;
    const float* nb = new_xyz + ((size_t)b * NPOINT + s) * 3;
    const float cx = nb[0], cy = nb[1], cz = nb[2];
    const float* xb = xyz + (size_t)b * NPTS * 3;
    const float r2 = (float)(0.2 * 0.2);
    int cnt = 0;
    int first = -1;
    int* out = gidx + (size_t)gw * NSAMPLE;
    for (int j0 = 0; j0 < NPTS; j0 += 64) {
        int j = j0 + lane;
        float dx = __fsub_rn(xb[j * 3 + 0], cx);
        float dy = __fsub_rn(xb[j * 3 + 1], cy);
        float dz = __fsub_rn(xb[j * 3 + 2], cz);
        float d = __fadd_rn(__fadd_rn(__fmul_rn(dx, dx), __fmul_rn(dy, dy)),
                            __fmul_rn(dz, dz));
        bool pred = !(d > r2);
        u64 mask = __ballot(pred);
        if (first < 0 && mask != 0ull) first = j0 + (__ffsll((long long)mask) - 1);
        int before = __popcll(mask & ((1ull << lane) - 1ull));
        int slot = cnt + before;
        if (pred && slot < NSAMPLE) out[slot] = j;
        cnt += (int)__popcll(mask);
        if (cnt >= NSAMPLE) break;
    }
    if (cnt < NSAMPLE) {
        if (lane >= cnt && lane < NSAMPLE) out[lane] = first;
    }
}

// ---------------------------------------------------------------- conv1 (gather + 35->64)
__global__ __launch_bounds__(256) void conv1_kernel(const float* __restrict__ xyz,
                                                    const float* __restrict__ points,
                                                    const float* __restrict__ new_xyz,
                                                    const int* __restrict__ gidx,
                                                    const float* __restrict__ W,
                                                    const float* __restrict__ bias,
                                                    ushort_t* __restrict__ Y) {
    const int p = blockIdx.x * 256 + threadIdx.x;
    const int b = p >> 15;
    const int rem = p & 32767;
    const int s = rem >> 5;
    const int j = gidx[p];
    float xin[35];
    const float* xp = xyz + ((size_t)b * NPTS + j) * 3;
    const float* nz = new_xyz + ((size_t)b * NPOINT + s) * 3;
    xin[0] = xp[0] - nz[0];
    xin[1] = xp[1] - nz[1];
    xin[2] = xp[2] - nz[2];
    const float4* pp = (const float4*)(points + ((size_t)b * NPTS + j) * 32);
#pragma unroll
    for (int i = 0; i < 8; i++) {
        float4 v = pp[i];
        xin[3 + 4 * i + 0] = v.x; xin[3 + 4 * i + 1] = v.y;
        xin[3 + 4 * i + 2] = v.z; xin[3 + 4 * i + 3] = v.w;
    }
    ushort_t* yo = Y + (size_t)p * 64;
#pragma unroll
    for (int og = 0; og < 8; og++) {
        float acc[8];
#pragma unroll
        for (int q = 0; q < 8; q++) acc[q] = bias[og * 8 + q];
#pragma unroll
        for (int i = 0; i < 35; i++) {
            float xv = xin[i];
#pragma unroll
            for (int q = 0; q < 8; q++)
                acc[q] = fmaf(W[(og * 8 + q) * 35 + i], xv, acc[q]);
        }
        *(uint4*)(yo + og * 8) = pack8(acc);
    }
}

// ---------------------------------------------------------------- convN (BN+ReLU on load)
template <int IN, int OUT>
__global__ __launch_bounds__(256) void convN_kernel(const ushort_t* __restrict__ Yin,
                                                    const float* __restrict__ scale,
                                                    const float* __restrict__ shift,
                                                    const float* __restrict__ W,
                                                    const float* __restrict__ bias,
                                                    ushort_t* __restrict__ Yout) {
    const int p = blockIdx.x * 256 + threadIdx.x;
    float xin[IN];
    const ushort_t* yi = Yin + (size_t)p * IN;
#pragma unroll
    for (int i = 0; i < IN; i += 8) {
        uint4 u = *(const uint4*)(yi + i);
        float f[8];
        unpack8(u, f);
#pragma unroll
        for (int q = 0; q < 8; q++)
            xin[i + q] = fmaxf(fmaf(f[q], scale[i + q], shift[i + q]), 0.f);
    }
    ushort_t* yo = Yout + (size_t)p * OUT;
#pragma unroll
    for (int og = 0; og < OUT / 8; og++) {
        float acc[8];
#pragma unroll
        for (int q = 0; q < 8; q++) acc[q] = bias[og * 8 + q];
#pragma unroll
        for (int i = 0; i < IN; i++) {
            float xv = xin[i];
#pragma unroll
            for (int q = 0; q < 8; q++)
                acc[q] = fmaf(W[(og * 8 + q) * IN + i], xv, acc[q]);
        }
        *(uint4*)(yo + og * 8) = pack8(acc);
    }
}

// ---------------------------------------------------------------- per-channel stats
// Wave-level shuffle reduction first => only 4 KiB LDS.
template <int OUT>
__global__ __launch_bounds__(256) void stats_kernel(const ushort_t* __restrict__ Y,
                                                    float* __restrict__ sums,
                                                    float* __restrict__ sq) {
    constexpr int CH8 = OUT / 8;       // 8 or 16
    constexpr int ROWS = 256 / CH8;    // 32 or 16
    constexpr int PPB = ROWS * 32;     // positions per block
    const int oc = threadIdx.x % CH8;
    const int row = threadIdx.x / CH8;
    const int p0 = blockIdx.x * PPB + row;
    float s[8], q[8];
#pragma unroll
    for (int i = 0; i < 8; i++) { s[i] = 0.f; q[i] = 0.f; }
    for (int jj = 0; jj < 32; jj++) {
        int p = p0 + jj * ROWS;
        uint4 u = *(const uint4*)(Y + (size_t)p * OUT + oc * 8);
        float f[8];
        unpack8(u, f);
#pragma unroll
        for (int i = 0; i < 8; i++) { s[i] += f[i]; q[i] += f[i] * f[i]; }
    }
    // intra-wave: lanes with the same oc differ only in bits >= log2(CH8)
#pragma unroll
    for (int m = CH8; m < 64; m <<= 1) {
#pragma unroll
        for (int i = 0; i < 8; i++) {
            s[i] += __shfl_xor(s[i], m, 64);
            q[i] += __shfl_xor(q[i], m, 64);
        }
    }
    __shared__ float lsq[4][CH8][16];
    const int wid = threadIdx.x >> 6, lane = threadIdx.x & 63;
    if (lane < CH8) {
#pragma unroll
        for (int i = 0; i < 8; i++) {
            lsq[wid][lane][i] = s[i];
            lsq[wid][lane][8 + i] = q[i];
        }
    }
    __syncthreads();
    if (threadIdx.x < OUT) {
        int ch = threadIdx.x;
        int oc2 = ch >> 3, i = ch & 7;
        float ssum = 0.f, qsum = 0.f;
#pragma unroll
        for (int w = 0; w < 4; w++) {
            ssum += lsq[w][oc2][i];
            qsum += lsq[w][oc2][8 + i];
        }
        atomicAdd(sums + ch, ssum);
        atomicAdd(sq + ch, qsum);
    }
}

// ---------------------------------------------------------------- finalize BN params
__global__ void finalize_kernel(const float* __restrict__ sums, const float* __restrict__ sq,
                                const float* __restrict__ g, const float* __restrict__ be,
                                float* __restrict__ scale, float* __restrict__ shift, int OUT) {
    int c = threadIdx.x;
    if (c < OUT) {
        float mean = sums[c] * (1.f / (float)NPOS);
        float var = sq[c] * (1.f / (float)NPOS) - mean * mean;
        float inv = 1.f / sqrtf(var + EPSV);
        float sc = g[c] * inv;
        scale[c] = sc;
        shift[c] = be[c] - mean * sc;
    }
}

// ---------------------------------------------------------------- BN3 + ReLU + max over k
__global__ __launch_bounds__(256) void final_kernel(const ushort_t* __restrict__ Y3,
                                                    const float* __restrict__ scale,
                                                    const float* __restrict__ shift,
                                                    float* __restrict__ out) {
    const int b = blockIdx.x >> 5;
    const int stile = (blockIdx.x & 31) * 32;
    const int sl = threadIdx.x >> 3;   // 0..31
    const int oc = threadIdx.x & 7;    // 0..7 -> channels oc*16..+16
    const int s = stile + sl;
    const size_t base = ((size_t)(b * NPOINT + s)) * 32 * 128 + oc * 16;
    float vmax[16];
#pragma unroll
    for (int i = 0; i < 16; i++) vmax[i] = 0.f;   // relu floor
    for (int k = 0; k < 32; k++) {
        const ushort_t* yp = Y3 + base + (size_t)k * 128;
#pragma unroll
        for (int h = 0; h < 2; h++) {
            uint4 u = *(const uint4*)(yp + h * 8);
            float f[8];
            unpack8(u, f);
#pragma unroll
            for (int i = 0; i < 8; i++) {
                int o = oc * 16 + h * 8 + i;
                float v = fmaf(f[i], scale[o], shift[o]);
                vmax[h * 8 + i] = fmaxf(vmax[h * 8 + i], v);
            }
        }
    }
    __shared__ float res[32][130];
#pragma unroll
    for (int i = 0; i < 16; i++) res[sl][oc * 16 + i] = vmax[i];
    __syncthreads();
    const int so = threadIdx.x & 31;
    const int og = threadIdx.x >> 5;   // 0..7
#pragma unroll
    for (int r = 0; r < 16; r++) {
        int o = og * 16 + r;
        out[((size_t)(b * 128 + o)) * NPOINT + stile + so] = res[so][o];
    }
}

// ---------------------------------------------------------------- launch
extern "C" void kernel_launch(void* const* d_in, const int* in_sizes, int n_in,
                              void* d_out, int out_size, void* d_ws, size_t ws_size,
                              hipStream_t stream) {
    const float* xyz = (const float*)d_in[0];
    const float* points = (const float*)d_in[1];
    const float* w0 = (const float*)d_in[2];
    const float* b0 = (const float*)d_in[3];
    const float* g0 = (const float*)d_in[4];
    const float* be0 = (const float*)d_in[5];
    const float* w1 = (const float*)d_in[6];
    const float* b1 = (const float*)d_in[7];
    const float* g1 = (const float*)d_in[8];
    const float* be1 = (const float*)d_in[9];
    const float* w2 = (const float*)d_in[10];
    const float* b2 = (const float*)d_in[11];
    const float* g2 = (const float*)d_in[12];
    const float* be2 = (const float*)d_in[13];

    float* out = (float*)d_out;
    float* new_xyz = out;                      // B*NPOINT*3 = 49152
    float* final_out = out + BATCH * NPOINT * 3;

    // workspace layout (194 MiB total; Y3 overlays Y1 -- Y1 dead after conv2)
    char* ws = (char*)d_ws;
    const size_t MB = 1024u * 1024u;
    const size_t o_gidx = 0;                          // 2 MiB
    const size_t o_y2 = 2 * MB;                       // 64 MiB (bf16 NPOS*64)
    const size_t o_y13 = o_y2 + (size_t)NPOS * 64 * 2;  // 128 MiB (Y1: first 64, Y3: all)
    const size_t o_stats = o_y13 + (size_t)NPOS * 128 * 2;  // 512 floats
    const size_t o_params = o_stats + 2048;           // 512 floats

    int* gidx = (int*)(ws + o_gidx);
    ushort_t* Y1 = (ushort_t*)(ws + o_y13);
    ushort_t* Y2 = (ushort_t*)(ws + o_y2);
    ushort_t* Y3 = (ushort_t*)(ws + o_y13);
    float* st = (float*)(ws + o_stats);
    float* sum1 = st + 0, *sq1 = st + 64;
    float* sum2 = st + 128, *sq2 = st + 192;
    float* sum3 = st + 256, *sq3 = st + 384;
    float* pr = (float*)(ws + o_params);
    float* scale1 = pr + 0, *shift1 = pr + 64;
    float* scale2 = pr + 128, *shift2 = pr + 192;
    float* scale3 = pr + 256, *shift3 = pr + 384;

    zero_kernel<<<1, 512, 0, stream>>>(st, 512);

    fps_kernel<<<BATCH, 1024, 0, stream>>>(xyz, new_xyz);
    ballq_kernel<<<(BATCH * NPOINT) / 4, 256, 0, stream>>>(xyz, new_xyz, gidx);
    conv1_kernel<<<NPOS / 256, 256, 0, stream>>>(xyz, points, new_xyz, gidx, w0, b0, Y1);
    stats_kernel<64><<<NPOS / 1024, 256, 0, stream>>>(Y1, sum1, sq1);
    finalize_kernel<<<1, 128, 0, stream>>>(sum1, sq1, g0, be0, scale1, shift1, 64);
    convN_kernel<64, 64><<<NPOS / 256, 256, 0, stream>>>(Y1, scale1, shift1, w1, b1, Y2);
    stats_kernel<64><<<NPOS / 1024, 256, 0, stream>>>(Y2, sum2, sq2);
    finalize_kernel<<<1, 128, 0, stream>>>(sum2, sq2, g1, be1, scale2, shift2, 64);
    convN_kernel<64, 128><<<NPOS / 256, 256, 0, stream>>>(Y2, scale2, shift2, w2, b2, Y3);
    stats_kernel<128><<<NPOS / 512, 256, 0, stream>>>(Y3, sum3, sq3);
    finalize_kernel<<<1, 128, 0, stream>>>(sum3, sq3, g2, be2, scale3, shift3, 128);
    final_kernel<<<BATCH * 32, 256, 0, stream>>>(Y3, scale3, shift3, final_out);
}

// Round 3
// 1682.312 us; speedup vs baseline: 1.2158x; 1.2158x over previous
//
#include <hip/hip_runtime.h>
#include <stdint.h>

#define BATCH   16
#define NPTS    4096
#define NPOINT  1024
#define NSAMPLE 32
#define NPOS    (BATCH*NPOINT*NSAMPLE)   // 524288
#define EPSV    1e-5f

typedef unsigned short ushort_t;
typedef unsigned int uint_t;
typedef unsigned long long u64;

__device__ inline ushort_t f2bf(float f) {
    uint_t u = __float_as_uint(f);
    u += 0x7fffu + ((u >> 16) & 1u);   // RNE (no NaNs in this workload)
    return (ushort_t)(u >> 16);
}
__device__ inline void unpack8(uint4 u, float* f) {
    f[0] = __uint_as_float(u.x << 16); f[1] = __uint_as_float(u.x & 0xffff0000u);
    f[2] = __uint_as_float(u.y << 16); f[3] = __uint_as_float(u.y & 0xffff0000u);
    f[4] = __uint_as_float(u.z << 16); f[5] = __uint_as_float(u.z & 0xffff0000u);
    f[6] = __uint_as_float(u.w << 16); f[7] = __uint_as_float(u.w & 0xffff0000u);
}
__device__ inline uint4 pack8(const float* a) {
    uint4 r;
    r.x = (uint_t)f2bf(a[0]) | ((uint_t)f2bf(a[1]) << 16);
    r.y = (uint_t)f2bf(a[2]) | ((uint_t)f2bf(a[3]) << 16);
    r.z = (uint_t)f2bf(a[4]) | ((uint_t)f2bf(a[5]) << 16);
    r.w = (uint_t)f2bf(a[6]) | ((uint_t)f2bf(a[7]) << 16);
    return r;
}

// ---------------------------------------------------------------- zero stats
__global__ void zero_kernel(float* __restrict__ p, int n) {
    int i = blockIdx.x * blockDim.x + threadIdx.x;
    if (i < n) p[i] = 0.f;
}

// ---------------------------------------------------------------- FPS
// One block per batch, 256 threads (1 wave/SIMD). 16 points/thread in regs.
// Per iter: local best -> 6-stage u64 wave shuffle -> parity-buffered LDS
// cross-wave reduce with ONE barrier; all threads redundantly compute the
// winner. Indices buffered in LDS; new_xyz written after the loop.
// Exact fp32 op order (no FMA contraction) to match np reference argmax.
__global__ __launch_bounds__(256) void fps_kernel(const float* __restrict__ xyz,
                                                  float* __restrict__ new_xyz) {
    __shared__ float4 lxyz[NPTS];     // 64 KiB, packed points
    __shared__ u64 wbest[2][4];
    __shared__ int fpsidx[NPOINT];    // 4 KiB
    const int b = blockIdx.x;
    const int tid = threadIdx.x;
    const float* base = xyz + (size_t)b * NPTS * 3;
    for (int n = tid; n < NPTS; n += 256) {
        lxyz[n] = make_float4(base[3 * n], base[3 * n + 1], base[3 * n + 2], 0.f);
    }
    __syncthreads();

    float px[16], py[16], pz[16], dist[16];
#pragma unroll
    for (int j = 0; j < 16; j++) {
        float4 v = lxyz[tid + j * 256];
        px[j] = v.x; py[j] = v.y; pz[j] = v.z;
        dist[j] = 1e10f;
    }
    if (tid == 0) fpsidx[0] = 0;
    int cur = 0;
    const int lane = tid & 63, wid = tid >> 6;

    for (int it = 1; it < NPOINT; ++it) {
        float4 c = lxyz[cur];
        float bd = -1.f; int bi = 0;
#pragma unroll
        for (int j = 0; j < 16; j++) {
            float dx = __fsub_rn(px[j], c.x);
            float dy = __fsub_rn(py[j], c.y);
            float dz = __fsub_rn(pz[j], c.z);
            float d = __fadd_rn(__fadd_rn(__fmul_rn(dx, dx), __fmul_rn(dy, dy)),
                                __fmul_rn(dz, dz));
            dist[j] = fminf(dist[j], d);
            // strict > keeps the smallest index on ties (idx grows with j)
            bool gt = dist[j] > bd;
            bd = gt ? dist[j] : bd;
            bi = gt ? tid + j * 256 : bi;
        }
        // dist >= 0 -> float bits order-preserving; ~idx -> smaller idx wins ties
        u64 best = ((u64)__float_as_uint(bd) << 32) | (uint_t)(~(uint_t)bi);
#pragma unroll
        for (int m = 32; m >= 1; m >>= 1) {
            u64 o = __shfl_xor(best, m, 64);
            best = o > best ? o : best;
        }
        const int par = it & 1;
        if (lane == 0) wbest[par][wid] = best;
        __syncthreads();
        u64 b0 = wbest[par][0], b1 = wbest[par][1];
        u64 b2 = wbest[par][2], b3 = wbest[par][3];
        u64 m01 = b0 > b1 ? b0 : b1;
        u64 m23 = b2 > b3 ? b2 : b3;
        u64 bb = m01 > m23 ? m01 : m23;
        cur = (int)(~(uint_t)(bb & 0xFFFFFFFFu)) & (NPTS - 1);
        if (tid == 0) fpsidx[it] = cur;
        // parity buffering makes a second barrier unnecessary: the next write
        // to wbest[par] only happens after everyone passed the NEXT barrier.
    }
    __syncthreads();
    float* ob = new_xyz + (size_t)b * NPOINT * 3;
    for (int s = tid; s < NPOINT; s += 256) {
        float4 v = lxyz[fpsidx[s]];
        ob[3 * s + 0] = v.x; ob[3 * s + 1] = v.y; ob[3 * s + 2] = v.z;
    }
}

// ---------------------------------------------------------------- ball query
// One wave per centroid; ordered compaction of first NSAMPLE in-radius idx.
__global__ __launch_bounds__(256) void ballq_kernel(const float* __restrict__ xyz,
                                                    const float* __restrict__ new_xyz,
                                                    int* __restrict__ gidx) {
    const int gw = (int)((blockIdx.x * 256 + threadIdx.x) >> 6);
    const int lane = threadIdx.x & 63;
    const int b = gw / NPOINT, s = gw % NPOINT;
    const float* nb = new_xyz + ((size_t)b * NPOINT + s) * 3;
    const float cx = nb[0], cy = nb[1], cz = nb[2];
    const float* xb = xyz + (size_t)b * NPTS * 3;
    const float r2 = (float)(0.2 * 0.2);
    int cnt = 0;
    int first = -1;
    int* out = gidx + (size_t)gw * NSAMPLE;
    for (int j0 = 0; j0 < NPTS; j0 += 64) {
        int j = j0 + lane;
        float dx = __fsub_rn(xb[j * 3 + 0], cx);
        float dy = __fsub_rn(xb[j * 3 + 1], cy);
        float dz = __fsub_rn(xb[j * 3 + 2], cz);
        float d = __fadd_rn(__fadd_rn(__fmul_rn(dx, dx), __fmul_rn(dy, dy)),
                            __fmul_rn(dz, dz));
        bool pred = !(d > r2);
        u64 mask = __ballot(pred);
        if (first < 0 && mask != 0ull) first = j0 + (__ffsll((long long)mask) - 1);
        int before = __popcll(mask & ((1ull << lane) - 1ull));
        int slot = cnt + before;
        if (pred && slot < NSAMPLE) out[slot] = j;
        cnt += (int)__popcll(mask);
        if (cnt >= NSAMPLE) break;
    }
    if (cnt < NSAMPLE) {
        if (lane >= cnt && lane < NSAMPLE) out[lane] = first;
    }
}

// ---------------------------------------------------------------- conv1 (gather + 35->64)
// Block: 256 thr = 4 waves x 64 positions; wave w -> channels 16w..16w+16.
// Weight indices are wave-uniform -> scalar loads.
__global__ __launch_bounds__(256) void conv1_kernel(const float* __restrict__ xyz,
                                                    const float* __restrict__ points,
                                                    const float* __restrict__ new_xyz,
                                                    const int* __restrict__ gidx,
                                                    const float* __restrict__ W,
                                                    const float* __restrict__ bias,
                                                    ushort_t* __restrict__ Y) {
    const int lane = threadIdx.x & 63;
    const int wid = __builtin_amdgcn_readfirstlane(threadIdx.x >> 6);
    const int p = blockIdx.x * 64 + lane;
    const int c0 = wid * 16;
    const int b = p >> 15;
    const int rem = p & 32767;
    const int s = rem >> 5;
    const int j = gidx[p];
    float xin[35];
    const float* xp = xyz + ((size_t)b * NPTS + j) * 3;
    const float* nz = new_xyz + ((size_t)b * NPOINT + s) * 3;
    xin[0] = xp[0] - nz[0];
    xin[1] = xp[1] - nz[1];
    xin[2] = xp[2] - nz[2];
    const float4* pp = (const float4*)(points + ((size_t)b * NPTS + j) * 32);
#pragma unroll
    for (int i = 0; i < 8; i++) {
        float4 v = pp[i];
        xin[3 + 4 * i + 0] = v.x; xin[3 + 4 * i + 1] = v.y;
        xin[3 + 4 * i + 2] = v.z; xin[3 + 4 * i + 3] = v.w;
    }
    float acc[16];
#pragma unroll
    for (int c = 0; c < 16; c++) acc[c] = bias[c0 + c];
    const float* Wr = W + (size_t)c0 * 35;
#pragma unroll 5
    for (int i = 0; i < 35; i++) {
        float xv = xin[i];
#pragma unroll
        for (int c = 0; c < 16; c++)
            acc[c] = fmaf(Wr[c * 35 + i], xv, acc[c]);
    }
    ushort_t* yo = Y + (size_t)p * 64 + c0;
    *(uint4*)(yo + 0) = pack8(acc + 0);
    *(uint4*)(yo + 8) = pack8(acc + 8);
}

// ---------------------------------------------------------------- convN (BN+ReLU on load)
// Block: OUT/16 waves x 64 positions; wave w -> 16 channels; scalar weights.
template <int IN, int OUT>
__global__ __launch_bounds__(OUT * 4) void convN_kernel(const ushort_t* __restrict__ Yin,
                                                        const float* __restrict__ scale,
                                                        const float* __restrict__ shift,
                                                        const float* __restrict__ W,
                                                        const float* __restrict__ bias,
                                                        ushort_t* __restrict__ Yout) {
    const int lane = threadIdx.x & 63;
    const int wid = __builtin_amdgcn_readfirstlane(threadIdx.x >> 6);
    const int p = blockIdx.x * 64 + lane;
    const int c0 = wid * 16;
    float xin[IN];
    const ushort_t* yi = Yin + (size_t)p * IN;
#pragma unroll
    for (int i = 0; i < IN; i += 8) {
        uint4 u = *(const uint4*)(yi + i);
        float f[8];
        unpack8(u, f);
#pragma unroll
        for (int q = 0; q < 8; q++)
            xin[i + q] = fmaxf(fmaf(f[q], scale[i + q], shift[i + q]), 0.f);
    }
    float acc[16];
#pragma unroll
    for (int c = 0; c < 16; c++) acc[c] = bias[c0 + c];
    const float* Wr = W + (size_t)c0 * IN;
#pragma unroll 8
    for (int i = 0; i < IN; i++) {
        float xv = xin[i];
#pragma unroll
        for (int c = 0; c < 16; c++)
            acc[c] = fmaf(Wr[c * IN + i], xv, acc[c]);
    }
    ushort_t* yo = Yout + (size_t)p * OUT + c0;
    *(uint4*)(yo + 0) = pack8(acc + 0);
    *(uint4*)(yo + 8) = pack8(acc + 8);
}

// ---------------------------------------------------------------- per-channel stats
// Wave-level shuffle reduction first => only 4 KiB LDS.
template <int OUT>
__global__ __launch_bounds__(256) void stats_kernel(const ushort_t* __restrict__ Y,
                                                    float* __restrict__ sums,
                                                    float* __restrict__ sq) {
    constexpr int CH8 = OUT / 8;       // 8 or 16
    constexpr int ROWS = 256 / CH8;    // 32 or 16
    constexpr int PPB = ROWS * 32;     // positions per block
    const int oc = threadIdx.x % CH8;
    const int row = threadIdx.x / CH8;
    const int p0 = blockIdx.x * PPB + row;
    float s[8], q[8];
#pragma unroll
    for (int i = 0; i < 8; i++) { s[i] = 0.f; q[i] = 0.f; }
    for (int jj = 0; jj < 32; jj++) {
        int p = p0 + jj * ROWS;
        uint4 u = *(const uint4*)(Y + (size_t)p * OUT + oc * 8);
        float f[8];
        unpack8(u, f);
#pragma unroll
        for (int i = 0; i < 8; i++) { s[i] += f[i]; q[i] += f[i] * f[i]; }
    }
#pragma unroll
    for (int m = CH8; m < 64; m <<= 1) {
#pragma unroll
        for (int i = 0; i < 8; i++) {
            s[i] += __shfl_xor(s[i], m, 64);
            q[i] += __shfl_xor(q[i], m, 64);
        }
    }
    __shared__ float lsq[4][CH8][16];
    const int wid = threadIdx.x >> 6, lane = threadIdx.x & 63;
    if (lane < CH8) {
#pragma unroll
        for (int i = 0; i < 8; i++) {
            lsq[wid][lane][i] = s[i];
            lsq[wid][lane][8 + i] = q[i];
        }
    }
    __syncthreads();
    if (threadIdx.x < OUT) {
        int ch = threadIdx.x;
        int oc2 = ch >> 3, i = ch & 7;
        float ssum = 0.f, qsum = 0.f;
#pragma unroll
        for (int w = 0; w < 4; w++) {
            ssum += lsq[w][oc2][i];
            qsum += lsq[w][oc2][8 + i];
        }
        atomicAdd(sums + ch, ssum);
        atomicAdd(sq + ch, qsum);
    }
}

// ---------------------------------------------------------------- finalize BN params
__global__ void finalize_kernel(const float* __restrict__ sums, const float* __restrict__ sq,
                                const float* __restrict__ g, const float* __restrict__ be,
                                float* __restrict__ scale, float* __restrict__ shift, int OUT) {
    int c = threadIdx.x;
    if (c < OUT) {
        float mean = sums[c] * (1.f / (float)NPOS);
        float var = sq[c] * (1.f / (float)NPOS) - mean * mean;
        float inv = 1.f / sqrtf(var + EPSV);
        float sc = g[c] * inv;
        scale[c] = sc;
        shift[c] = be[c] - mean * sc;
    }
}

// ---------------------------------------------------------------- BN3 + ReLU + max over k
__global__ __launch_bounds__(256) void final_kernel(const ushort_t* __restrict__ Y3,
                                                    const float* __restrict__ scale,
                                                    const float* __restrict__ shift,
                                                    float* __restrict__ out) {
    const int b = blockIdx.x >> 5;
    const int stile = (blockIdx.x & 31) * 32;
    const int sl = threadIdx.x >> 3;   // 0..31
    const int oc = threadIdx.x & 7;    // 0..7 -> channels oc*16..+16
    const int s = stile + sl;
    const size_t base = ((size_t)(b * NPOINT + s)) * 32 * 128 + oc * 16;
    float vmax[16];
#pragma unroll
    for (int i = 0; i < 16; i++) vmax[i] = 0.f;   // relu floor
    for (int k = 0; k < 32; k++) {
        const ushort_t* yp = Y3 + base + (size_t)k * 128;
#pragma unroll
        for (int h = 0; h < 2; h++) {
            uint4 u = *(const uint4*)(yp + h * 8);
            float f[8];
            unpack8(u, f);
#pragma unroll
            for (int i = 0; i < 8; i++) {
                int o = oc * 16 + h * 8 + i;
                float v = fmaf(f[i], scale[o], shift[o]);
                vmax[h * 8 + i] = fmaxf(vmax[h * 8 + i], v);
            }
        }
    }
    __shared__ float res[32][130];
#pragma unroll
    for (int i = 0; i < 16; i++) res[sl][oc * 16 + i] = vmax[i];
    __syncthreads();
    const int so = threadIdx.x & 31;
    const int og = threadIdx.x >> 5;   // 0..7
#pragma unroll
    for (int r = 0; r < 16; r++) {
        int o = og * 16 + r;
        out[((size_t)(b * 128 + o)) * NPOINT + stile + so] = res[so][o];
    }
}

// ---------------------------------------------------------------- launch
extern "C" void kernel_launch(void* const* d_in, const int* in_sizes, int n_in,
                              void* d_out, int out_size, void* d_ws, size_t ws_size,
                              hipStream_t stream) {
    const float* xyz = (const float*)d_in[0];
    const float* points = (const float*)d_in[1];
    const float* w0 = (const float*)d_in[2];
    const float* b0 = (const float*)d_in[3];
    const float* g0 = (const float*)d_in[4];
    const float* be0 = (const float*)d_in[5];
    const float* w1 = (const float*)d_in[6];
    const float* b1 = (const float*)d_in[7];
    const float* g1 = (const float*)d_in[8];
    const float* be1 = (const float*)d_in[9];
    const float* w2 = (const float*)d_in[10];
    const float* b2 = (const float*)d_in[11];
    const float* g2 = (const float*)d_in[12];
    const float* be2 = (const float*)d_in[13];

    float* out = (float*)d_out;
    float* new_xyz = out;                      // B*NPOINT*3 = 49152
    float* final_out = out + BATCH * NPOINT * 3;

    // workspace layout (194 MiB total; Y3 overlays Y1 -- Y1 dead after conv2)
    char* ws = (char*)d_ws;
    const size_t MB = 1024u * 1024u;
    const size_t o_gidx = 0;                          // 2 MiB
    const size_t o_y2 = 2 * MB;                       // 64 MiB (bf16 NPOS*64)
    const size_t o_y13 = o_y2 + (size_t)NPOS * 64 * 2;  // 128 MiB (Y1: first 64, Y3: all)
    const size_t o_stats = o_y13 + (size_t)NPOS * 128 * 2;  // 512 floats
    const size_t o_params = o_stats + 2048;           // 512 floats

    int* gidx = (int*)(ws + o_gidx);
    ushort_t* Y1 = (ushort_t*)(ws + o_y13);
    ushort_t* Y2 = (ushort_t*)(ws + o_y2);
    ushort_t* Y3 = (ushort_t*)(ws + o_y13);
    float* st = (float*)(ws + o_stats);
    float* sum1 = st + 0, *sq1 = st + 64;
    float* sum2 = st + 128, *sq2 = st + 192;
    float* sum3 = st + 256, *sq3 = st + 384;
    float* pr = (float*)(ws + o_params);
    float* scale1 = pr + 0, *shift1 = pr + 64;
    float* scale2 = pr + 128, *shift2 = pr + 192;
    float* scale3 = pr + 256, *shift3 = pr + 384;

    zero_kernel<<<1, 512, 0, stream>>>(st, 512);

    fps_kernel<<<BATCH, 256, 0, stream>>>(xyz, new_xyz);
    ballq_kernel<<<(BATCH * NPOINT) / 4, 256, 0, stream>>>(xyz, new_xyz, gidx);
    conv1_kernel<<<NPOS / 64, 256, 0, stream>>>(xyz, points, new_xyz, gidx, w0, b0, Y1);
    stats_kernel<64><<<NPOS / 1024, 256, 0, stream>>>(Y1, sum1, sq1);
    finalize_kernel<<<1, 128, 0, stream>>>(sum1, sq1, g0, be0, scale1, shift1, 64);
    convN_kernel<64, 64><<<NPOS / 64, 256, 0, stream>>>(Y1, scale1, shift1, w1, b1, Y2);
    stats_kernel<64><<<NPOS / 1024, 256, 0, stream>>>(Y2, sum2, sq2);
    finalize_kernel<<<1, 128, 0, stream>>>(sum2, sq2, g1, be1, scale2, shift2, 64);
    convN_kernel<64, 128><<<NPOS / 64, 512, 0, stream>>>(Y2, scale2, shift2, w2, b2, Y3);
    stats_kernel<128><<<NPOS / 512, 256, 0, stream>>>(Y3, sum3, sq3);
    finalize_kernel<<<1, 128, 0, stream>>>(sum3, sq3, g2, be2, scale3, shift3, 128);
    final_kernel<<<BATCH * 32, 256, 0, stream>>>(Y3, scale3, shift3, final_out);
}

// Round 4
// 1075.590 us; speedup vs baseline: 1.9017x; 1.5641x over previous
//
#include <hip/hip_runtime.h>
#include <stdint.h>

#define BATCH   16
#define NPTS    4096
#define NPOINT  1024
#define NSAMPLE 32
#define NPOS    (BATCH*NPOINT*NSAMPLE)   // 524288
#define EPSV    1e-5f

typedef unsigned short ushort_t;
typedef unsigned int uint_t;
typedef unsigned long long u64;
typedef __attribute__((ext_vector_type(8))) short bf16x8;
typedef __attribute__((ext_vector_type(4))) float f32x4;

__device__ inline ushort_t f2bf(float f) {
    uint_t u = __float_as_uint(f);
    u += 0x7fffu + ((u >> 16) & 1u);   // RNE (no NaNs in this workload)
    return (ushort_t)(u >> 16);
}
__device__ inline void unpack8(uint4 u, float* f) {
    f[0] = __uint_as_float(u.x << 16); f[1] = __uint_as_float(u.x & 0xffff0000u);
    f[2] = __uint_as_float(u.y << 16); f[3] = __uint_as_float(u.y & 0xffff0000u);
    f[4] = __uint_as_float(u.z << 16); f[5] = __uint_as_float(u.z & 0xffff0000u);
    f[6] = __uint_as_float(u.w << 16); f[7] = __uint_as_float(u.w & 0xffff0000u);
}
__device__ inline uint4 pack8(const float* a) {
    uint4 r;
    r.x = (uint_t)f2bf(a[0]) | ((uint_t)f2bf(a[1]) << 16);
    r.y = (uint_t)f2bf(a[2]) | ((uint_t)f2bf(a[3]) << 16);
    r.z = (uint_t)f2bf(a[4]) | ((uint_t)f2bf(a[5]) << 16);
    r.w = (uint_t)f2bf(a[6]) | ((uint_t)f2bf(a[7]) << 16);
    return r;
}

// ---------------------------------------------------------------- zero stats
__global__ void zero_kernel(float* __restrict__ p, int n) {
    int i = blockIdx.x * blockDim.x + threadIdx.x;
    if (i < n) p[i] = 0.f;
}

// ---------------------------------------------------------------- FPS
// One block per batch, 256 threads. 16 pts/thread in regs. Per iter:
// packed-u64 local TREE reduce (depth 4) -> DPP wave reduce (VALU-latency,
// no ds_swizzle) -> readlane(63) -> parity-LDS cross-wave reduce, 1 barrier.
// Exact fp32 op order (no FMA contraction) to match np reference argmax.
#define DPP_MAX_STAGE(CTRL) do {                                              \
    uint_t _lo2 = __builtin_amdgcn_update_dpp(lo, lo, CTRL, 0xf, 0xf, false); \
    uint_t _hi2 = __builtin_amdgcn_update_dpp(hi, hi, CTRL, 0xf, 0xf, false); \
    u64 _o = ((u64)_hi2 << 32) | _lo2;                                        \
    u64 _v = ((u64)hi << 32) | lo;                                            \
    bool _g = _o > _v;                                                        \
    lo = _g ? _lo2 : lo; hi = _g ? _hi2 : hi;                                 \
} while (0)

__global__ __launch_bounds__(256) void fps_kernel(const float* __restrict__ xyz,
                                                  float* __restrict__ new_xyz) {
    __shared__ float4 lxyz[NPTS];     // 64 KiB
    __shared__ u64 wbest[2][4];
    __shared__ int fpsidx[NPOINT];
    const int b = blockIdx.x;
    const int tid = threadIdx.x;
    const float* base = xyz + (size_t)b * NPTS * 3;
    for (int n = tid; n < NPTS; n += 256) {
        lxyz[n] = make_float4(base[3 * n], base[3 * n + 1], base[3 * n + 2], 0.f);
    }
    __syncthreads();

    float px[16], py[16], pz[16], dist[16];
    uint_t lowc[16];   // ~idx, iteration-invariant (smaller idx wins ties)
#pragma unroll
    for (int j = 0; j < 16; j++) {
        float4 v = lxyz[tid + j * 256];
        px[j] = v.x; py[j] = v.y; pz[j] = v.z;
        dist[j] = 1e10f;
        lowc[j] = ~(uint_t)(tid + j * 256);
    }
    if (tid == 0) fpsidx[0] = 0;
    int cur = 0;
    const int lane = tid & 63, wid = tid >> 6;

    for (int it = 1; it < NPOINT; ++it) {
        float4 c = lxyz[cur];
#pragma unroll
        for (int j = 0; j < 16; j++) {
            float dx = __fsub_rn(px[j], c.x);
            float dy = __fsub_rn(py[j], c.y);
            float dz = __fsub_rn(pz[j], c.z);
            float d = __fadd_rn(__fadd_rn(__fmul_rn(dx, dx), __fmul_rn(dy, dy)),
                                __fmul_rn(dz, dz));
            dist[j] = fminf(dist[j], d);
        }
        // tree reduce 16 packed u64 (dist >= 0 -> bits order-preserving)
        u64 t[8];
#pragma unroll
        for (int j = 0; j < 8; j++) {
            u64 a = ((u64)__float_as_uint(dist[j]) << 32) | lowc[j];
            u64 d2 = ((u64)__float_as_uint(dist[j + 8]) << 32) | lowc[j + 8];
            t[j] = a > d2 ? a : d2;
        }
#pragma unroll
        for (int j = 0; j < 4; j++) { u64 o = t[j + 4]; t[j] = t[j] > o ? t[j] : o; }
        t[0] = t[0] > t[1] ? t[0] : t[1];
        t[2] = t[2] > t[3] ? t[2] : t[3];
        u64 v = t[0] > t[2] ? t[0] : t[2];

        uint_t lo = (uint_t)v, hi = (uint_t)(v >> 32);
        DPP_MAX_STAGE(0x111);   // row_shr:1
        DPP_MAX_STAGE(0x112);   // row_shr:2
        DPP_MAX_STAGE(0x114);   // row_shr:4
        DPP_MAX_STAGE(0x118);   // row_shr:8
        DPP_MAX_STAGE(0x142);   // row_bcast:15
        DPP_MAX_STAGE(0x143);   // row_bcast:31
        uint_t mlo = __builtin_amdgcn_readlane(lo, 63);
        uint_t mhi = __builtin_amdgcn_readlane(hi, 63);

        const int par = it & 1;
        if (lane == 0) wbest[par][wid] = ((u64)mhi << 32) | mlo;
        __syncthreads();
        u64 b0 = wbest[par][0], b1 = wbest[par][1];
        u64 b2 = wbest[par][2], b3 = wbest[par][3];
        u64 m01 = b0 > b1 ? b0 : b1;
        u64 m23 = b2 > b3 ? b2 : b3;
        u64 bb = m01 > m23 ? m01 : m23;
        cur = (int)(~(uint_t)bb) & (NPTS - 1);
        if (tid == 0) fpsidx[it] = cur;
        // parity buffering: next write to this slot is 2 barriers away -> safe
    }
    __syncthreads();
    float* ob = new_xyz + (size_t)b * NPOINT * 3;
    for (int s = tid; s < NPOINT; s += 256) {
        float4 v = lxyz[fpsidx[s]];
        ob[3 * s + 0] = v.x; ob[3 * s + 1] = v.y; ob[3 * s + 2] = v.z;
    }
}

// ---------------------------------------------------------------- ball query
__global__ __launch_bounds__(256) void ballq_kernel(const float* __restrict__ xyz,
                                                    const float* __restrict__ new_xyz,
                                                    int* __restrict__ gidx) {
    const int gw = (int)((blockIdx.x * 256 + threadIdx.x) >> 6);
    const int lane = threadIdx.x & 63;
    const int b = gw / NPOINT, s = gw % NPOINT;
    const float* nb = new_xyz + ((size_t)b * NPOINT + s) * 3;
    const float cx = nb[0], cy = nb[1], cz = nb[2];
    const float* xb = xyz + (size_t)b * NPTS * 3;
    const float r2 = (float)(0.2 * 0.2);
    int cnt = 0;
    int first = -1;
    int* out = gidx + (size_t)gw * NSAMPLE;
    for (int j0 = 0; j0 < NPTS; j0 += 64) {
        int j = j0 + lane;
        float dx = __fsub_rn(xb[j * 3 + 0], cx);
        float dy = __fsub_rn(xb[j * 3 + 1], cy);
        float dz = __fsub_rn(xb[j * 3 + 2], cz);
        float d = __fadd_rn(__fadd_rn(__fmul_rn(dx, dx), __fmul_rn(dy, dy)),
                            __fmul_rn(dz, dz));
        bool pred = !(d > r2);
        u64 mask = __ballot(pred);
        if (first < 0 && mask != 0ull) first = j0 + (__ffsll((long long)mask) - 1);
        int before = __popcll(mask & ((1ull << lane) - 1ull));
        int slot = cnt + before;
        if (pred && slot < NSAMPLE) out[slot] = j;
        cnt += (int)__popcll(mask);
        if (cnt >= NSAMPLE) break;
    }
    if (cnt < NSAMPLE) {
        if (lane >= cnt && lane < NSAMPLE) out[lane] = first;
    }
}

// ---------------------------------------------------------------- conv1 (MFMA)
// 128 positions/block, 4 waves x 32 pos (2 m-tiles). K split: points ch (32)
// as one MFMA slice, xyz-norm (3) in k=0..2 of a sparse second slice.
__global__ __launch_bounds__(256) void conv1_mfma(const float* __restrict__ xyz,
                                                  const float* __restrict__ points,
                                                  const float* __restrict__ new_xyz,
                                                  const int* __restrict__ gidx,
                                                  const float* __restrict__ W,
                                                  const float* __restrict__ bias,
                                                  ushort_t* __restrict__ Y) {
    const int lane = threadIdx.x & 63, wid = threadIdx.x >> 6;
    const int l15 = lane & 15, quad = lane >> 4;
    const int p0 = blockIdx.x * 128 + wid * 32;

    bf16x8 Bp[4], Bx[4];
#pragma unroll
    for (int nt = 0; nt < 4; nt++) {
        const float* wr = W + (size_t)(nt * 16 + l15) * 35;
#pragma unroll
        for (int q = 0; q < 8; q++) Bp[nt][q] = (short)f2bf(wr[3 + quad * 8 + q]);
#pragma unroll
        for (int q = 0; q < 8; q++)
            Bx[nt][q] = (quad == 0 && q < 3) ? (short)f2bf(wr[q]) : (short)0;
    }
    f32x4 acc[2][4];
#pragma unroll
    for (int mt = 0; mt < 2; mt++)
#pragma unroll
        for (int nt = 0; nt < 4; nt++) acc[mt][nt] = (f32x4){0.f, 0.f, 0.f, 0.f};

#pragma unroll
    for (int mt = 0; mt < 2; mt++) {
        const int p = p0 + mt * 16 + l15;
        const int b = p >> 15, s = (p & 32767) >> 5;
        const int j = gidx[p];
        const float* pr = points + ((size_t)(b * NPTS + j)) * 32 + quad * 8;
        bf16x8 Ap, Ax;
#pragma unroll
        for (int q = 0; q < 8; q++) Ap[q] = (short)f2bf(pr[q]);
#pragma unroll
        for (int q = 0; q < 8; q++) Ax[q] = 0;
        const float* xp = xyz + ((size_t)(b * NPTS + j)) * 3;
        const float* nz = new_xyz + ((size_t)(b * NPOINT + s)) * 3;
        if (quad == 0) {
            Ax[0] = (short)f2bf(xp[0] - nz[0]);
            Ax[1] = (short)f2bf(xp[1] - nz[1]);
            Ax[2] = (short)f2bf(xp[2] - nz[2]);
        }
#pragma unroll
        for (int nt = 0; nt < 4; nt++) {
            acc[mt][nt] = __builtin_amdgcn_mfma_f32_16x16x32_bf16(Ap, Bp[nt], acc[mt][nt], 0, 0, 0);
            acc[mt][nt] = __builtin_amdgcn_mfma_f32_16x16x32_bf16(Ax, Bx[nt], acc[mt][nt], 0, 0, 0);
        }
    }
#pragma unroll
    for (int nt = 0; nt < 4; nt++) {
        const int ch = nt * 16 + l15;
        const float bs = bias[ch];
#pragma unroll
        for (int mt = 0; mt < 2; mt++) {
            const int pb = p0 + mt * 16 + quad * 4;
#pragma unroll
            for (int r = 0; r < 4; r++)
                Y[(size_t)(pb + r) * 64 + ch] = f2bf(acc[mt][nt][r] + bs);
        }
    }
}

// ---------------------------------------------------------------- convN (MFMA, BN+ReLU on load)
template <int IN, int OUT>
__global__ __launch_bounds__(256) void convN_mfma(const ushort_t* __restrict__ Yin,
                                                  const float* __restrict__ scale,
                                                  const float* __restrict__ shift,
                                                  const float* __restrict__ W,
                                                  const float* __restrict__ bias,
                                                  ushort_t* __restrict__ Yout) {
    constexpr int NT = OUT / 16;
    const int lane = threadIdx.x & 63, wid = threadIdx.x >> 6;
    const int l15 = lane & 15, quad = lane >> 4;
    const int p0 = blockIdx.x * 128 + wid * 32;

    float sc[2][8], sh[2][8];
#pragma unroll
    for (int kq = 0; kq < 2; kq++) {
        const int i0 = kq * 32 + quad * 8;
#pragma unroll
        for (int q = 0; q < 8; q++) { sc[kq][q] = scale[i0 + q]; sh[kq][q] = shift[i0 + q]; }
    }
    bf16x8 Bf[NT][2];
#pragma unroll
    for (int nt = 0; nt < NT; nt++)
#pragma unroll
        for (int kq = 0; kq < 2; kq++) {
            const float* wr = W + (size_t)(nt * 16 + l15) * IN + kq * 32 + quad * 8;
#pragma unroll
            for (int q = 0; q < 8; q++) Bf[nt][kq][q] = (short)f2bf(wr[q]);
        }

    bf16x8 Af[2][2];
#pragma unroll
    for (int mt = 0; mt < 2; mt++)
#pragma unroll
        for (int kq = 0; kq < 2; kq++) {
            const ushort_t* yr = Yin + (size_t)(p0 + mt * 16 + l15) * IN + kq * 32 + quad * 8;
            uint4 u = *(const uint4*)yr;
            float f[8]; unpack8(u, f);
#pragma unroll
            for (int q = 0; q < 8; q++) {
                float x = fmaxf(fmaf(f[q], sc[kq][q], sh[kq][q]), 0.f);
                Af[mt][kq][q] = (short)f2bf(x);
            }
        }

    f32x4 acc[2][NT];
#pragma unroll
    for (int mt = 0; mt < 2; mt++)
#pragma unroll
        for (int nt = 0; nt < NT; nt++) acc[mt][nt] = (f32x4){0.f, 0.f, 0.f, 0.f};
#pragma unroll
    for (int mt = 0; mt < 2; mt++)
#pragma unroll
        for (int nt = 0; nt < NT; nt++) {
            acc[mt][nt] = __builtin_amdgcn_mfma_f32_16x16x32_bf16(Af[mt][0], Bf[nt][0], acc[mt][nt], 0, 0, 0);
            acc[mt][nt] = __builtin_amdgcn_mfma_f32_16x16x32_bf16(Af[mt][1], Bf[nt][1], acc[mt][nt], 0, 0, 0);
        }
#pragma unroll
    for (int nt = 0; nt < NT; nt++) {
        const int ch = nt * 16 + l15;
        const float bs = bias[ch];
#pragma unroll
        for (int mt = 0; mt < 2; mt++) {
            const int pb = p0 + mt * 16 + quad * 4;
#pragma unroll
            for (int r = 0; r < 4; r++)
                Yout[(size_t)(pb + r) * OUT + ch] = f2bf(acc[mt][nt][r] + bs);
        }
    }
}

// ---------------------------------------------------------------- per-channel stats
template <int OUT>
__global__ __launch_bounds__(256) void stats_kernel(const ushort_t* __restrict__ Y,
                                                    float* __restrict__ sums,
                                                    float* __restrict__ sq) {
    constexpr int CH8 = OUT / 8;
    constexpr int ROWS = 256 / CH8;
    constexpr int PPB = ROWS * 32;
    const int oc = threadIdx.x % CH8;
    const int row = threadIdx.x / CH8;
    const int p0 = blockIdx.x * PPB + row;
    float s[8], q[8];
#pragma unroll
    for (int i = 0; i < 8; i++) { s[i] = 0.f; q[i] = 0.f; }
    for (int jj = 0; jj < 32; jj++) {
        int p = p0 + jj * ROWS;
        uint4 u = *(const uint4*)(Y + (size_t)p * OUT + oc * 8);
        float f[8];
        unpack8(u, f);
#pragma unroll
        for (int i = 0; i < 8; i++) { s[i] += f[i]; q[i] += f[i] * f[i]; }
    }
#pragma unroll
    for (int m = CH8; m < 64; m <<= 1) {
#pragma unroll
        for (int i = 0; i < 8; i++) {
            s[i] += __shfl_xor(s[i], m, 64);
            q[i] += __shfl_xor(q[i], m, 64);
        }
    }
    __shared__ float lsq[4][CH8][16];
    const int wid = threadIdx.x >> 6, lane = threadIdx.x & 63;
    if (lane < CH8) {
#pragma unroll
        for (int i = 0; i < 8; i++) {
            lsq[wid][lane][i] = s[i];
            lsq[wid][lane][8 + i] = q[i];
        }
    }
    __syncthreads();
    if (threadIdx.x < OUT) {
        int ch = threadIdx.x;
        int oc2 = ch >> 3, i = ch & 7;
        float ssum = 0.f, qsum = 0.f;
#pragma unroll
        for (int w = 0; w < 4; w++) {
            ssum += lsq[w][oc2][i];
            qsum += lsq[w][oc2][8 + i];
        }
        atomicAdd(sums + ch, ssum);
        atomicAdd(sq + ch, qsum);
    }
}

// ---------------------------------------------------------------- finalize BN params
__global__ void finalize_kernel(const float* __restrict__ sums, const float* __restrict__ sq,
                                const float* __restrict__ g, const float* __restrict__ be,
                                float* __restrict__ scale, float* __restrict__ shift, int OUT) {
    int c = threadIdx.x;
    if (c < OUT) {
        float mean = sums[c] * (1.f / (float)NPOS);
        float var = sq[c] * (1.f / (float)NPOS) - mean * mean;
        float inv = 1.f / sqrtf(var + EPSV);
        float sc = g[c] * inv;
        scale[c] = sc;
        shift[c] = be[c] - mean * sc;
    }
}

// ---------------------------------------------------------------- BN3 + ReLU + max over k
__global__ __launch_bounds__(256) void final_kernel(const ushort_t* __restrict__ Y3,
                                                    const float* __restrict__ scale,
                                                    const float* __restrict__ shift,
                                                    float* __restrict__ out) {
    const int b = blockIdx.x >> 5;
    const int stile = (blockIdx.x & 31) * 32;
    const int sl = threadIdx.x >> 3;
    const int oc = threadIdx.x & 7;
    const int s = stile + sl;
    const size_t base = ((size_t)(b * NPOINT + s)) * 32 * 128 + oc * 16;
    float vmax[16];
#pragma unroll
    for (int i = 0; i < 16; i++) vmax[i] = 0.f;
    for (int k = 0; k < 32; k++) {
        const ushort_t* yp = Y3 + base + (size_t)k * 128;
#pragma unroll
        for (int h = 0; h < 2; h++) {
            uint4 u = *(const uint4*)(yp + h * 8);
            float f[8];
            unpack8(u, f);
#pragma unroll
            for (int i = 0; i < 8; i++) {
                int o = oc * 16 + h * 8 + i;
                float v = fmaf(f[i], scale[o], shift[o]);
                vmax[h * 8 + i] = fmaxf(vmax[h * 8 + i], v);
            }
        }
    }
    __shared__ float res[32][130];
#pragma unroll
    for (int i = 0; i < 16; i++) res[sl][oc * 16 + i] = vmax[i];
    __syncthreads();
    const int so = threadIdx.x & 31;
    const int og = threadIdx.x >> 5;
#pragma unroll
    for (int r = 0; r < 16; r++) {
        int o = og * 16 + r;
        out[((size_t)(b * 128 + o)) * NPOINT + stile + so] = res[so][o];
    }
}

// ---------------------------------------------------------------- launch
extern "C" void kernel_launch(void* const* d_in, const int* in_sizes, int n_in,
                              void* d_out, int out_size, void* d_ws, size_t ws_size,
                              hipStream_t stream) {
    const float* xyz = (const float*)d_in[0];
    const float* points = (const float*)d_in[1];
    const float* w0 = (const float*)d_in[2];
    const float* b0 = (const float*)d_in[3];
    const float* g0 = (const float*)d_in[4];
    const float* be0 = (const float*)d_in[5];
    const float* w1 = (const float*)d_in[6];
    const float* b1 = (const float*)d_in[7];
    const float* g1 = (const float*)d_in[8];
    const float* be1 = (const float*)d_in[9];
    const float* w2 = (const float*)d_in[10];
    const float* b2 = (const float*)d_in[11];
    const float* g2 = (const float*)d_in[12];
    const float* be2 = (const float*)d_in[13];

    float* out = (float*)d_out;
    float* new_xyz = out;                      // B*NPOINT*3 = 49152
    float* final_out = out + BATCH * NPOINT * 3;

    // workspace layout (194 MiB; Y3 overlays Y1 -- Y1 dead after conv2)
    char* ws = (char*)d_ws;
    const size_t MB = 1024u * 1024u;
    const size_t o_gidx = 0;
    const size_t o_y2 = 2 * MB;
    const size_t o_y13 = o_y2 + (size_t)NPOS * 64 * 2;
    const size_t o_stats = o_y13 + (size_t)NPOS * 128 * 2;
    const size_t o_params = o_stats + 2048;

    int* gidx = (int*)(ws + o_gidx);
    ushort_t* Y1 = (ushort_t*)(ws + o_y13);
    ushort_t* Y2 = (ushort_t*)(ws + o_y2);
    ushort_t* Y3 = (ushort_t*)(ws + o_y13);
    float* st = (float*)(ws + o_stats);
    float* sum1 = st + 0, *sq1 = st + 64;
    float* sum2 = st + 128, *sq2 = st + 192;
    float* sum3 = st + 256, *sq3 = st + 384;
    float* pr = (float*)(ws + o_params);
    float* scale1 = pr + 0, *shift1 = pr + 64;
    float* scale2 = pr + 128, *shift2 = pr + 192;
    float* scale3 = pr + 256, *shift3 = pr + 384;

    zero_kernel<<<1, 512, 0, stream>>>(st, 512);

    fps_kernel<<<BATCH, 256, 0, stream>>>(xyz, new_xyz);
    ballq_kernel<<<(BATCH * NPOINT) / 4, 256, 0, stream>>>(xyz, new_xyz, gidx);
    conv1_mfma<<<NPOS / 128, 256, 0, stream>>>(xyz, points, new_xyz, gidx, w0, b0, Y1);
    stats_kernel<64><<<NPOS / 1024, 256, 0, stream>>>(Y1, sum1, sq1);
    finalize_kernel<<<1, 128, 0, stream>>>(sum1, sq1, g0, be0, scale1, shift1, 64);
    convN_mfma<64, 64><<<NPOS / 128, 256, 0, stream>>>(Y1, scale1, shift1, w1, b1, Y2);
    stats_kernel<64><<<NPOS / 1024, 256, 0, stream>>>(Y2, sum2, sq2);
    finalize_kernel<<<1, 128, 0, stream>>>(sum2, sq2, g1, be1, scale2, shift2, 64);
    convN_mfma<64, 128><<<NPOS / 128, 256, 0, stream>>>(Y2, scale2, shift2, w2, b2, Y3);
    stats_kernel<128><<<NPOS / 512, 256, 0, stream>>>(Y3, sum3, sq3);
    finalize_kernel<<<1, 128, 0, stream>>>(sum3, sq3, g2, be2, scale3, shift3, 128);
    final_kernel<<<BATCH * 32, 256, 0, stream>>>(Y3, scale3, shift3, final_out);
}